// Round 7
// baseline (117.083 us; speedup 1.0000x reference)
//
#include <hip/hip_runtime.h>
#include <hip/hip_cooperative_groups.h>

namespace cg = cooperative_groups;

// Problem constants (fixed by the reference):
//   x: (B=2, C=64, H=16, W=64) fp32; S = H*W = 1024; heads g=64, per-head c=1.
//   scores[s,t] = q_s * k_t / 8 ; softmax over t ; o_s = sum_t p_st * v_t
//
// Rank-1 trick: with c=1, o_s = f(p_s), a scalar analytic function:
//   f(p) = sum_t 2^(p k_t) v_t / sum_t 2^(p k_t),  p = q_s * (1/8) * log2(e)
// 16-node Chebyshev interpolation of numerator & denominator over the head's
// exact range [-pmax, pmax]: rel err ~ I_16(pmax*kmax*ln2) ~ 1e-9 typical,
// ~1e-6 at 5-sigma -- threshold is 8.8e-2. Exps: 134M -> 2.1M.
//
// Single cooperative kernel: phase 1 (QKV + Chebyshev attention -> O in ws),
// grid.sync(), phase 2 (output projection + residual). Block = head = (b,o);
// in phase 2 the same block index gives a block-uniform output channel o, so
// the Wo row stays on the scalar path.
#define BB    2
#define CC    64
#define SS    1024
#define PSC   (0.125f * 1.44269504f)   // (1/sqrt(64)) * log2(e)
#define PI_F  3.14159265358979f
#define NCHEB 16

#if __has_builtin(__builtin_amdgcn_exp2f)
#define EXP2(x) __builtin_amdgcn_exp2f(x)   // bare v_exp_f32
#else
#define EXP2(x) exp2f(x)
#endif

__global__ __launch_bounds__(1024) void fused_attn_kernel(
    const float* __restrict__ x,
    const float* __restrict__ Wq, const float* __restrict__ bq,
    const float* __restrict__ Wk, const float* __restrict__ bk,
    const float* __restrict__ Wv, const float* __restrict__ bv,
    const float* __restrict__ Wo, const float* __restrict__ bo,
    float* __restrict__ O,              // ws: 128*1024 floats
    float* __restrict__ out)
{
    const int head = blockIdx.x;        // [0,128)
    const int b    = head >> 6;
    const int o    = head & 63;
    const int tid  = threadIdx.x;       // [0,1024)
    const int lane = tid & 63;
    const int wv   = tid >> 6;          // wave id, [0,16)

    __shared__ float ks[SS], vs[SS], ps[SS];
    __shared__ float wred[16];
    __shared__ float Fse[NCHEB], Fsv[NCHEB];
    __shared__ float cse[NCHEB], csv[NCHEB];

    // ---- phase 1a: project q,k,v for position t = tid
    const float* __restrict__ wq  = Wq + o * CC;   // block-uniform -> s_load
    const float* __restrict__ wk  = Wk + o * CC;
    const float* __restrict__ wvp = Wv + o * CC;
    const float* __restrict__ xb  = x + b * CC * SS + tid;

    float qa = bq[o], ka = bk[o], va = bv[o];
    #pragma unroll 16
    for (int c = 0; c < CC; ++c) {
        const float xv = xb[c * SS];    // lane-consecutive -> coalesced
        qa = fmaf(wq[c],  xv, qa);
        ka = fmaf(wk[c],  xv, ka);
        va = fmaf(wvp[c], xv, va);
    }
    ks[tid] = ka;
    vs[tid] = va;
    const float p = qa * PSC;
    ps[tid] = p;

    // pmax reduction: wave max of |p|, then 16 partials in LDS
    float am = fabsf(p);
    #pragma unroll
    for (int off = 32; off; off >>= 1)
        am = fmaxf(am, __shfl_xor(am, off, 64));
    if (lane == 0) wred[wv] = am;
    __syncthreads();

    float pmax = wred[0];
    #pragma unroll
    for (int i = 1; i < 16; ++i) pmax = fmaxf(pmax, wred[i]);
    pmax = fmaxf(pmax, 1e-20f);         // degenerate all-zero-q guard

    // ---- phase 1b: nodal sums; wave j owns Chebyshev node j
    const float pj = pmax * __cosf((2 * wv + 1) * (PI_F / (2 * NCHEB)));
    float se = 0.f, sv = 0.f;
    #pragma unroll
    for (int i = 0; i < 16; ++i) {
        const int t = lane + 64 * i;    // stride-1 across lanes: conflict-free
        const float e = EXP2(pj * ks[t]);
        se += e;
        sv = fmaf(e, vs[t], sv);
    }
    #pragma unroll
    for (int off = 32; off; off >>= 1) {
        se += __shfl_xor(se, off, 64);
        sv += __shfl_xor(sv, off, 64);
    }
    if (lane == 0) { Fse[wv] = se; Fsv[wv] = sv; }
    __syncthreads();

    // ---- phase 1c: DCT -> Chebyshev coefficients (2 functions x 16 coeffs)
    if (tid < 2 * NCHEB) {
        const int  n  = tid & (NCHEB - 1);
        const bool fn = tid >= NCHEB;
        const float* __restrict__ F = fn ? Fsv : Fse;
        float acc = 0.f;
        #pragma unroll
        for (int j = 0; j < NCHEB; ++j)
            acc = fmaf(F[j], __cosf(n * (2 * j + 1) * (PI_F / (2 * NCHEB))), acc);
        acc *= (n == 0) ? (1.f / NCHEB) : (2.f / NCHEB);
        (fn ? csv : cse)[n] = acc;
    }
    __syncthreads();

    // ---- phase 1d: per-row Clenshaw evaluation, write O row
    {
        const float u  = ps[tid] / pmax;    // in [-1,1] by construction
        const float tu = 2.f * u;
        float b1 = 0.f, b2 = 0.f, d1 = 0.f, d2 = 0.f;
        #pragma unroll
        for (int n = NCHEB - 1; n >= 1; --n) {
            const float nb = fmaf(tu, b1, cse[n] - b2);
            b2 = b1; b1 = nb;
            const float nd = fmaf(tu, d1, csv[n] - d2);
            d2 = d1; d1 = nd;
        }
        const float fse = fmaf(u, b1, cse[0] - b2);
        const float fsv = fmaf(u, d1, csv[0] - d2);
        O[head * SS + tid] = fsv / fse;     // coalesced
    }

    // ---- grid-wide barrier: all O rows visible device-wide
    cg::this_grid().sync();

    // ---- phase 2: output projection + residual for row (b, o), col s = tid
    const float* __restrict__ wo = Wo + o * CC;    // block-uniform -> s_load
    const float* __restrict__ Ob = O + b * CC * SS + tid;
    float acc = bo[o];
    #pragma unroll 16
    for (int c = 0; c < CC; ++c)
        acc = fmaf(wo[c], Ob[c * SS], acc);        // lanes coalesced per c

    const int idx = head * SS + tid;               // == ((b*64)+o)*1024 + s
    out[idx] = x[idx] + acc;
}

extern "C" void kernel_launch(void* const* d_in, const int* in_sizes, int n_in,
                              void* d_out, int out_size, void* d_ws, size_t ws_size,
                              hipStream_t stream) {
    const float* x  = (const float*)d_in[0];
    const float* Wq = (const float*)d_in[1];
    const float* bq = (const float*)d_in[2];
    const float* Wk = (const float*)d_in[3];
    const float* bk = (const float*)d_in[4];
    const float* Wv = (const float*)d_in[5];
    const float* bv = (const float*)d_in[6];
    const float* Wo = (const float*)d_in[7];
    const float* bo = (const float*)d_in[8];
    float* out = (float*)d_out;
    float* O   = (float*)d_ws;          // 512 KB of workspace used

    void* args[] = {
        (void*)&x,  (void*)&Wq, (void*)&bq, (void*)&Wk, (void*)&bk,
        (void*)&Wv, (void*)&bv, (void*)&Wo, (void*)&bo, (void*)&O, (void*)&out
    };
    hipLaunchCooperativeKernel((const void*)fused_attn_kernel,
                               dim3(128), dim3(1024), args, 0, stream);
}

// Round 8
// 79.437 us; speedup vs baseline: 1.4739x; 1.4739x over previous
//
#include <hip/hip_runtime.h>

// Problem constants (fixed by the reference):
//   x: (B=2, C=64, H=16, W=64) fp32; S = H*W = 1024; heads g=64, per-head c=1.
//   scores[s,t] = q_s * k_t / 8 ; softmax over t ; o_s = sum_t p_st * v_t
//
// Rank-1 trick: with c=1, o_s = f(p_s), a scalar analytic function:
//   f(p) = sum_t 2^(p k_t) v_t / sum_t 2^(p k_t),  p = q_s * (1/8) * log2(e)
// 16-node Chebyshev interpolation of numerator & denominator over the head's
// exact range [-pmax, pmax]: rel err ~ I_16(pmax*kmax*ln2) ~ 1e-9 typical,
// ~1e-6 at 5-sigma -- threshold is 8.8e-2. Exps: 134M -> 2.1M.
//
// NOTE (R7 lesson): hipLaunchCooperativeKernel costs ~+37 us per graph replay
// on this harness -- plain back-to-back stream launches are strictly better.
#define BB    2
#define CC    64
#define SS    1024
#define PSC   (0.125f * 1.44269504f)   // (1/sqrt(64)) * log2(e)
#define PI_F  3.14159265358979f
#define NCHEB 16

#if __has_builtin(__builtin_amdgcn_exp2f)
#define EXP2(x) __builtin_amdgcn_exp2f(x)   // bare v_exp_f32
#else
#define EXP2(x) exp2f(x)
#endif

// -------- Kernel A: fused QKV projection + Chebyshev rank-1 attention --------
// Grid = 128 blocks (one per head=(b,o)) x 1024 threads (16 waves).
__global__ __launch_bounds__(1024) void qkv_cheb_attn_kernel(
    const float* __restrict__ x,
    const float* __restrict__ Wq, const float* __restrict__ bq,
    const float* __restrict__ Wk, const float* __restrict__ bk,
    const float* __restrict__ Wv, const float* __restrict__ bv,
    float* __restrict__ O)
{
    const int head = blockIdx.x;        // [0,128)
    const int b    = head >> 6;
    const int o    = head & 63;
    const int tid  = threadIdx.x;       // [0,1024)
    const int lane = tid & 63;
    const int wv   = tid >> 6;          // wave id, [0,16)

    __shared__ float ks[SS], vs[SS], ps[SS];
    __shared__ float wred[16];
    __shared__ float Fse[NCHEB], Fsv[NCHEB];
    __shared__ float cse[NCHEB], csv[NCHEB];

    // ---- A1: project q,k,v for position t = tid
    const float* __restrict__ wq  = Wq + o * CC;   // block-uniform -> s_load
    const float* __restrict__ wk  = Wk + o * CC;
    const float* __restrict__ wvp = Wv + o * CC;
    const float* __restrict__ xb  = x + b * CC * SS + tid;

    float qa = bq[o], ka = bk[o], va = bv[o];
    #pragma unroll 16
    for (int c = 0; c < CC; ++c) {
        const float xv = xb[c * SS];    // lane-consecutive -> coalesced
        qa = fmaf(wq[c],  xv, qa);
        ka = fmaf(wk[c],  xv, ka);
        va = fmaf(wvp[c], xv, va);
    }
    ks[tid] = ka;
    vs[tid] = va;
    const float p = qa * PSC;
    ps[tid] = p;

    // pmax reduction: wave max of |p|, then 16 partials in LDS
    float am = fabsf(p);
    #pragma unroll
    for (int off = 32; off; off >>= 1)
        am = fmaxf(am, __shfl_xor(am, off, 64));
    if (lane == 0) wred[wv] = am;
    __syncthreads();

    float pmax = wred[0];
    #pragma unroll
    for (int i = 1; i < 16; ++i) pmax = fmaxf(pmax, wred[i]);
    pmax = fmaxf(pmax, 1e-20f);         // degenerate all-zero-q guard

    // ---- A2: nodal sums; wave j owns Chebyshev node j
    const float pj = pmax * __cosf((2 * wv + 1) * (PI_F / (2 * NCHEB)));
    float se = 0.f, sv = 0.f;
    #pragma unroll
    for (int i = 0; i < 16; ++i) {
        const int t = lane + 64 * i;    // stride-1 across lanes: conflict-free
        const float e = EXP2(pj * ks[t]);
        se += e;
        sv = fmaf(e, vs[t], sv);
    }
    #pragma unroll
    for (int off = 32; off; off >>= 1) {
        se += __shfl_xor(se, off, 64);
        sv += __shfl_xor(sv, off, 64);
    }
    if (lane == 0) { Fse[wv] = se; Fsv[wv] = sv; }
    __syncthreads();

    // ---- A3: DCT -> Chebyshev coefficients (2 functions x 16 coeffs)
    if (tid < 2 * NCHEB) {
        const int  n  = tid & (NCHEB - 1);
        const bool fn = tid >= NCHEB;
        const float* __restrict__ F = fn ? Fsv : Fse;
        float acc = 0.f;
        #pragma unroll
        for (int j = 0; j < NCHEB; ++j)
            acc = fmaf(F[j], __cosf(n * (2 * j + 1) * (PI_F / (2 * NCHEB))), acc);
        acc *= (n == 0) ? (1.f / NCHEB) : (2.f / NCHEB);
        (fn ? csv : cse)[n] = acc;
    }
    __syncthreads();

    // ---- A4: per-row Clenshaw evaluation of both interpolants
    const float u  = ps[tid] / pmax;    // in [-1,1] by construction
    const float tu = 2.f * u;
    float b1 = 0.f, b2 = 0.f, d1 = 0.f, d2 = 0.f;
    #pragma unroll
    for (int n = NCHEB - 1; n >= 1; --n) {
        const float nb = fmaf(tu, b1, cse[n] - b2);
        b2 = b1; b1 = nb;
        const float nd = fmaf(tu, d1, csv[n] - d2);
        d2 = d1; d1 = nd;
    }
    const float fse = fmaf(u, b1, cse[0] - b2);
    const float fsv = fmaf(u, d1, csv[0] - d2);
    O[head * SS + tid] = fsv / fse;     // coalesced
}

// ---------------- Kernel B: output projection + residual (float2) ----------
// 2 columns per thread: out[b,o,s:s+2] = x[..] + dot(Wo[o,:], O[b,:,s:s+2]) + bo[o]
// Wo row block-uniform -> scalar path; O/x reads are global_load_dwordx2.
__global__ __launch_bounds__(256) void proj_kernel(
    const float* __restrict__ x, const float* __restrict__ O,
    const float* __restrict__ Wo, const float* __restrict__ bo,
    float* __restrict__ out)
{
    const int bid = blockIdx.x;          // [0,256)
    const int b   = bid >> 7;
    const int rem = bid & 127;
    const int o   = rem >> 1;            // output channel (block-uniform)
    const int sc  = rem & 1;
    const int s2  = (sc << 8) + threadIdx.x;   // float2 index in [0,512)

    const float* __restrict__ wo = Wo + o * CC;
    const float2* __restrict__ Ob = (const float2*)(O + b * CC * SS) + s2;

    const float bias = bo[o];
    float ax = bias, ay = bias;
    #pragma unroll 16
    for (int c = 0; c < CC; ++c) {
        const float2 ov = Ob[c * (SS / 2)];    // coalesced dwordx2
        const float w = wo[c];
        ax = fmaf(w, ov.x, ax);
        ay = fmaf(w, ov.y, ay);
    }
    const int idx2 = (b * CC + o) * (SS / 2) + s2;
    const float2 xv = ((const float2*)x)[idx2];
    ((float2*)out)[idx2] = make_float2(xv.x + ax, xv.y + ay);
}

extern "C" void kernel_launch(void* const* d_in, const int* in_sizes, int n_in,
                              void* d_out, int out_size, void* d_ws, size_t ws_size,
                              hipStream_t stream) {
    const float* x  = (const float*)d_in[0];
    const float* Wq = (const float*)d_in[1];
    const float* bq = (const float*)d_in[2];
    const float* Wk = (const float*)d_in[3];
    const float* bk = (const float*)d_in[4];
    const float* Wv = (const float*)d_in[5];
    const float* bv = (const float*)d_in[6];
    const float* Wo = (const float*)d_in[7];
    const float* bo = (const float*)d_in[8];
    float* out = (float*)d_out;

    float* O = (float*)d_ws;            // 512 KB of workspace used

    qkv_cheb_attn_kernel<<<128, 1024, 0, stream>>>(x, Wq, bq, Wk, bk, Wv, bv, O);
    proj_kernel         <<<256,  256, 0, stream>>>(x, O, Wo, bo, out);
}